// Round 1
// baseline (55.940 us; speedup 1.0000x reference)
//
#include <hip/hip_runtime.h>
#include <cmath>

namespace {

constexpr int Bb   = 128;
constexpr int Nn   = 32;
constexpr int Tt   = 50;
constexpr int Hh   = 128;
constexpr int HOPS = 8;
constexpr int NT   = Nn * Tt;                  // 1600
constexpr int POS_PER_BLOCK = 64;
constexpr int CHUNKS = NT / POS_PER_BLOCK;     // 25

// Kernel A: s1[b][nt][a] = (sum_h neigh[b,nt,h]*node[b,t,h]*W[a,h] + bias[a]) / sqrt(nn[0])
// written into the BA slot (temporary layout), plus neigh -> neigh_r passthrough copy.
__global__ __launch_bounds__(256) void ga_s1_copy(
    const float* __restrict__ node,     // [B][T][H]
    const float* __restrict__ neigh,    // [B][NT][H]
    const int*   __restrict__ nn,       // [B]
    const float* __restrict__ W,        // [HOPS][H]
    const float* __restrict__ bias,     // [HOPS]
    float* __restrict__ s1g,            // [B][NT][HOPS]  (aliases BA output slot)
    float* __restrict__ neigh_r)        // [B][NT][H]
{
    const int lane16 = threadIdx.x & 15;   // h-slice owner within a 16-lane group
    const int group  = threadIdx.x >> 4;   // 0..15 position groups per pass
    const int chunk  = blockIdx.x % CHUNKS;
    const int b      = blockIdx.x / CHUNKS;

    const float rscale = rsqrtf((float)nn[0]);

    // W fragment for this thread's fixed h-slice (h = lane16*8 .. +7): 64 regs
    float4 w0[HOPS], w1[HOPS];
    #pragma unroll
    for (int a = 0; a < HOPS; ++a) {
        const float4* wp = reinterpret_cast<const float4*>(W + a * Hh + lane16 * 8);
        w0[a] = wp[0];
        w1[a] = wp[1];
    }
    float bia[HOPS];
    #pragma unroll
    for (int a = 0; a < HOPS; ++a) bia[a] = bias[a];

    #pragma unroll
    for (int pass = 0; pass < 4; ++pass) {
        const int pos = chunk * POS_PER_BLOCK + pass * 16 + group;  // 0..1599
        const int t   = pos % Tt;

        const int nidx = (b * NT + pos) * Hh + lane16 * 8;
        const float4* np4 = reinterpret_cast<const float4*>(neigh + nidx);
        const float4 n0 = np4[0];
        const float4 n1 = np4[1];

        // fused passthrough copy (exact f32)
        float4* cp4 = reinterpret_cast<float4*>(neigh_r + nidx);
        cp4[0] = n0;
        cp4[1] = n1;

        const float4* dp4 = reinterpret_cast<const float4*>(node + (b * Tt + t) * Hh + lane16 * 8);
        const float4 d0 = dp4[0];
        const float4 d1 = dp4[1];

        const float4 p0 = make_float4(n0.x * d0.x, n0.y * d0.y, n0.z * d0.z, n0.w * d0.w);
        const float4 p1 = make_float4(n1.x * d1.x, n1.y * d1.y, n1.z * d1.z, n1.w * d1.w);

        float acc[HOPS];
        #pragma unroll
        for (int a = 0; a < HOPS; ++a) {
            acc[a] = p0.x * w0[a].x + p0.y * w0[a].y + p0.z * w0[a].z + p0.w * w0[a].w
                   + p1.x * w1[a].x + p1.y * w1[a].y + p1.z * w1[a].z + p1.w * w1[a].w;
        }
        // reduce across the 16 lanes of the group (xor masks 1,2,4,8 stay in-group)
        #pragma unroll
        for (int a = 0; a < HOPS; ++a) {
            acc[a] += __shfl_xor(acc[a], 1, 64);
            acc[a] += __shfl_xor(acc[a], 2, 64);
            acc[a] += __shfl_xor(acc[a], 4, 64);
            acc[a] += __shfl_xor(acc[a], 8, 64);
        }
        if (lane16 == 0) {
            const float4 o0 = make_float4((acc[0] + bia[0]) * rscale,
                                          (acc[1] + bia[1]) * rscale,
                                          (acc[2] + bia[2]) * rscale,
                                          (acc[3] + bia[3]) * rscale);
            const float4 o1 = make_float4((acc[4] + bia[4]) * rscale,
                                          (acc[5] + bia[5]) * rscale,
                                          (acc[6] + bia[6]) * rscale,
                                          (acc[7] + bia[7]) * rscale);
            float4* sp = reinterpret_cast<float4*>(s1g + (b * NT + pos) * HOPS);
            sp[0] = o0;
            sp[1] = o1;
        }
    }
}

// Kernel B: per-b softmax over NT per hop; rewrites BA slot [b][nt][a] -> [b][a][nt]
// (softmaxed) in place (all source values staged in LDS first), and BW = sum_a BA.
__global__ __launch_bounds__(256) void ga_softmax(float* __restrict__ out)
{
    float* BW = out;                       // [B][NT]
    float* BA = out + Bb * NT;             // [B][HOPS][NT]; currently holds s1 [B][NT][HOPS]
    const int b   = blockIdx.x;
    const int tid = threadIdx.x;

    __shared__ float s[NT * 9];            // +1 pad per row: stride 9, conflict-free columns
    __shared__ float sm_m[HOPS], sm_inv[HOPS];

    const float* src = BA + (size_t)b * NT * HOPS;
    for (int idx = tid; idx < NT * HOPS; idx += 256) {
        const int nt = idx >> 3;
        const int a  = idx & 7;
        s[nt * 9 + a] = src[idx];
    }
    __syncthreads();

    const int w    = tid >> 6;   // wave 0..3 -> hops {2w, 2w+1}
    const int lane = tid & 63;
    #pragma unroll
    for (int rep = 0; rep < 2; ++rep) {
        const int a = w * 2 + rep;
        float m = -INFINITY;
        for (int nt = lane; nt < NT; nt += 64) m = fmaxf(m, s[nt * 9 + a]);
        #pragma unroll
        for (int off = 32; off >= 1; off >>= 1) m = fmaxf(m, __shfl_xor(m, off, 64));
        float sum = 0.f;
        for (int nt = lane; nt < NT; nt += 64) sum += __expf(s[nt * 9 + a] - m);
        #pragma unroll
        for (int off = 32; off >= 1; off >>= 1) sum += __shfl_xor(sum, off, 64);
        if (lane == 0) { sm_m[a] = m; sm_inv[a] = 1.0f / sum; }
    }
    __syncthreads();

    float bw[7] = {0.f, 0.f, 0.f, 0.f, 0.f, 0.f, 0.f};
    float* bab = BA + (size_t)b * HOPS * NT;
    #pragma unroll
    for (int a = 0; a < HOPS; ++a) {
        const float m   = sm_m[a];
        const float inv = sm_inv[a];
        #pragma unroll
        for (int k = 0; k < 7; ++k) {
            const int nt = tid + k * 256;
            if (nt < NT) {
                const float v = __expf(s[nt * 9 + a] - m) * inv;
                bab[a * NT + nt] = v;   // coalesced per hop-plane
                bw[k] += v;
            }
        }
    }
    float* bwb = BW + (size_t)b * NT;
    #pragma unroll
    for (int k = 0; k < 7; ++k) {
        const int nt = tid + k * 256;
        if (nt < NT) bwb[nt] = bw[k];
    }
}

} // namespace

extern "C" void kernel_launch(void* const* d_in, const int* in_sizes, int n_in,
                              void* d_out, int out_size, void* d_ws, size_t ws_size,
                              hipStream_t stream) {
    const float* node  = (const float*)d_in[0];   // [128][50][128] f32
    const float* neigh = (const float*)d_in[1];   // [128][32][50][128] f32
    const int*   nn    = (const int*)d_in[2];     // [128] i32
    const float* W     = (const float*)d_in[3];   // [8][128] f32
    const float* bias  = (const float*)d_in[4];   // [8] f32

    float* out     = (float*)d_out;
    float* BA      = out + Bb * NT;            // after BW (204800)
    float* neigh_r = BA + Bb * HOPS * NT;      // after BA (1638400)

    ga_s1_copy<<<dim3(Bb * CHUNKS), dim3(256), 0, stream>>>(node, neigh, nn, W, bias, BA, neigh_r);
    ga_softmax<<<dim3(Bb), dim3(256), 0, stream>>>(out);
}